// Round 11
// baseline (300.064 us; speedup 1.0000x reference)
//
#include <hip/hip_runtime.h>
#include <math.h>

#define B_ 32
#define H_ 64
#define W_ 48
#define C_ 256
#define G_ 8
#define D_ 32
#define BG_ (B_*G_)          // 256
#define LN_EPS_ 1e-3f
#define NPIX_ (H_*W_)        // 3072
#define SROWB 3072           // bytes per LDS image row: 48 px * 32 ch * 2B

typedef short bf16x8 __attribute__((ext_vector_type(8)));
typedef float f32x4 __attribute__((ext_vector_type(4)));

__device__ __forceinline__ float sigmoidf_(float v) { return 1.0f / (1.0f + expf(-v)); }

__device__ __forceinline__ unsigned short f2bf(float f) {
    unsigned u = __float_as_uint(f);
    u = u + 0x7fffu + ((u >> 16) & 1u);
    return (unsigned short)(u >> 16);
}
__device__ __forceinline__ float bflo(unsigned u) { return __uint_as_float(u << 16); }
__device__ __forceinline__ float bfhi(unsigned u) { return __uint_as_float(u & 0xffff0000u); }

// swizzled in-row byte offset for (px, 16B-slot)
__device__ __forceinline__ int swz16(int px, int slot) {
    return ((px << 6) + (slot << 4)) ^ ((px & 7) << 4);
}

// ---------------------------------------------------------------------------
// K0: conv3x3 weights -> bf16, layout wbf[tap][e][d]
// ---------------------------------------------------------------------------
__global__ __launch_bounds__(256) void k0_prep(const float* __restrict__ w3,
                                               unsigned short* __restrict__ wbf)
{
    int i = blockIdx.x * 256 + threadIdx.x;
    if (i < 9 * D_ * D_) {
        int t = i >> 10;
        int rem = i & 1023;
        int e = rem >> 5, d = rem & 31;
        wbf[i] = f2bf(w3[((t << 5) + d) * D_ + e]);
    }
}

// ---------------------------------------------------------------------------
// K1: per bg (grid=256, 512 thr): row/col sums, 1x1 conv + sigmoid ->
// xhb/xwb (bf16), closed-form s2 (exact fp32 algebra). Single x pass.
// ---------------------------------------------------------------------------
__global__ __launch_bounds__(512) void k1_sums(const float* __restrict__ x,
                                               const float* __restrict__ w1,
                                               const float* __restrict__ b1,
                                               const float* __restrict__ w3,
                                               const float* __restrict__ b3,
                                               unsigned short* __restrict__ xhb,
                                               unsigned short* __restrict__ xwb,
                                               float* __restrict__ s2)
{
    __shared__ float mh[H_][D_];          // raw row sums (over w)
    __shared__ float mwp[8][W_][D_];      // per-wave col partials; mwp[0]=total
    __shared__ float wls[D_ * D_];
    __shared__ float cst[4][D_];          // corners
    __shared__ float Tg[D_];
    __shared__ float Sl[9][D_];
    __shared__ float S2p[9][D_];

    int bg = blockIdx.x;
    int b = bg >> 3, gi = bg & 7;
    const float* base = x + (size_t)b * H_ * W_ * C_ + gi * D_;
    int t = threadIdx.x;
    int lane = t & 63;
    int wv = t >> 6;
    int c4 = lane & 7;
    int pxg = lane >> 3;

    for (int i = t; i < D_ * D_; i += 512) wls[i] = w1[i];

    float4 colp[6];
    #pragma unroll
    for (int j = 0; j < 6; ++j) colp[j] = make_float4(0.f, 0.f, 0.f, 0.f);

    for (int i = 0; i < 8; i += 2) {
        int ha = (wv << 3) + i;
        int hb = ha + 1;
        const float* rowa = base + (size_t)ha * W_ * C_;
        const float* rowb = base + (size_t)hb * W_ * C_;
        float4 va[6], vb[6];
        #pragma unroll
        for (int j = 0; j < 6; ++j) {
            va[j] = *(const float4*)(rowa + (size_t)(pxg + 8 * j) * C_ + (c4 << 2));
            vb[j] = *(const float4*)(rowb + (size_t)(pxg + 8 * j) * C_ + (c4 << 2));
        }
        float4 rpa = make_float4(0.f, 0.f, 0.f, 0.f);
        float4 rpb = make_float4(0.f, 0.f, 0.f, 0.f);
        #pragma unroll
        for (int j = 0; j < 6; ++j) {
            float4 v = va[j];
            colp[j].x += v.x; colp[j].y += v.y; colp[j].z += v.z; colp[j].w += v.w;
            rpa.x += v.x; rpa.y += v.y; rpa.z += v.z; rpa.w += v.w;
            float4 u = vb[j];
            colp[j].x += u.x; colp[j].y += u.y; colp[j].z += u.z; colp[j].w += u.w;
            rpb.x += u.x; rpb.y += u.y; rpb.z += u.z; rpb.w += u.w;
        }
        #pragma unroll
        for (int s = 8; s <= 32; s <<= 1) {
            rpa.x += __shfl_xor(rpa.x, s); rpa.y += __shfl_xor(rpa.y, s);
            rpa.z += __shfl_xor(rpa.z, s); rpa.w += __shfl_xor(rpa.w, s);
            rpb.x += __shfl_xor(rpb.x, s); rpb.y += __shfl_xor(rpb.y, s);
            rpb.z += __shfl_xor(rpb.z, s); rpb.w += __shfl_xor(rpb.w, s);
        }
        if (lane < 8) {
            *(float4*)&mh[ha][c4 << 2] = rpa;
            *(float4*)&mh[hb][c4 << 2] = rpb;
        }
    }
    #pragma unroll
    for (int j = 0; j < 6; ++j)
        *(float4*)&mwp[wv][pxg + 8 * j][c4 << 2] = colp[j];
    __syncthreads();

    for (int i = t; i < W_ * D_; i += 512) {
        int px = i >> 5, c = i & 31;
        float s = 0.f;
        #pragma unroll
        for (int v = 0; v < 8; ++v) s += mwp[v][px][c];
        mwp[0][px][c] = s;
    }
    if (t < 128) {
        int k = t >> 5, c = t & 31;
        int hh = (k >> 1) ? (H_ - 1) : 0;
        int ww = (k & 1) ? (W_ - 1) : 0;
        cst[k][c] = base[(size_t)(hh * W_ + ww) * C_ + c];
    }
    __syncthreads();

    if (t < 32) {
        float s = 0.f;
        for (int h = 0; h < H_; ++h) s += mh[h][t];
        Tg[t] = s;
    }
    // 1x1 conv + sigmoid -> bf16 global
    for (int i = t; i < (H_ + W_) * D_; i += 512) {
        int pos = i >> 5, e = i & 31;
        const float* m = (pos < H_) ? mh[pos] : mwp[0][pos - H_];
        float scale = (pos < H_) ? (1.0f / W_) : (1.0f / H_);
        float dot = 0.f;
        #pragma unroll
        for (int d = 0; d < D_; ++d) dot += m[d] * wls[d * D_ + e];
        float sg = sigmoidf_(b1[e] + dot * scale);
        if (pos < H_) xhb[(((size_t)bg << 6) + pos) * D_ + e] = f2bf(sg);
        else          xwb[((size_t)bg * W_ + (pos - H_)) * D_ + e] = f2bf(sg);
    }
    __syncthreads();

    // closed-form s2
    if (t < 288) {
        int tap = t >> 5, d = t & 31;
        int dh = tap / 3, dw = tap % 3;
        float S = Tg[d];
        if (dh == 0) S -= mh[H_ - 1][d];
        else if (dh == 2) S -= mh[0][d];
        if (dw == 0) S -= mwp[0][W_ - 1][d];
        else if (dw == 2) S -= mwp[0][0][d];
        if (dh != 1 && dw != 1) S += cst[(dh == 0 ? 2 : 0) + (dw == 0 ? 1 : 0)][d];
        Sl[tap][d] = S;
    }
    __syncthreads();
    if (t < 288) {
        int tap = t >> 5, e = t & 31;
        float a = 0.f;
        #pragma unroll
        for (int d = 0; d < D_; ++d) a += w3[((tap << 5) + d) * D_ + e] * Sl[tap][d];
        S2p[tap][e] = a;
    }
    __syncthreads();
    if (t < 32) {
        float a = (float)NPIX_ * b3[t];
        #pragma unroll
        for (int tap = 0; tap < 9; ++tap) a += S2p[tap][t];
        s2[bg * D_ + t] = a;
    }
}

// ---------------------------------------------------------------------------
// K2: s1 = sum over pixels of x1 (LN(gx*xh*xw)*gamma+beta). grid = BG*4
// (16 rows each), 256 thr. x re-read is L3-warm. atomicAdd into s1.
// ---------------------------------------------------------------------------
__global__ __launch_bounds__(256) void k2_s1(const float* __restrict__ x,
                                             const unsigned short* __restrict__ xhb,
                                             const unsigned short* __restrict__ xwb,
                                             const float* __restrict__ gamma,
                                             const float* __restrict__ beta,
                                             float* __restrict__ s1)
{
    __shared__ float red[4][D_];
    int bi = blockIdx.x;
    int bg = bi >> 2;
    int h0 = (bi & 3) << 4;
    int b = bg >> 3, gi = bg & 7;
    const float* base = x + (size_t)b * H_ * W_ * C_ + gi * D_;
    int t = threadIdx.x;
    int lane = t & 63;
    int wv = t >> 6;

    float s1p[32];
    #pragma unroll
    for (int c = 0; c < 32; ++c) s1p[c] = 0.f;

    #pragma unroll
    for (int k = 0; k < 3; ++k) {
        int p = t + (k << 8);
        int r = p / W_;
        int w = p - r * W_;
        int h = h0 + r;
        const float4* vp = (const float4*)(base + (size_t)(h * W_ + w) * C_);
        const uint4* ph4 = (const uint4*)(xhb + (((size_t)bg << 6) + h) * D_);
        const uint4* pw4 = (const uint4*)(xwb + ((size_t)bg * W_ + w) * D_);
        float y[32];
        float mu = 0.f;
        #pragma unroll
        for (int j = 0; j < 4; ++j) {
            float4 v0 = vp[2 * j], v1 = vp[2 * j + 1];
            uint4 uh = ph4[j];
            uint4 uw = pw4[j];
            float vv[8] = {v0.x, v0.y, v0.z, v0.w, v1.x, v1.y, v1.z, v1.w};
            float ah[8], aw[8];
            ah[0]=bflo(uh.x); ah[1]=bfhi(uh.x); ah[2]=bflo(uh.y); ah[3]=bfhi(uh.y);
            ah[4]=bflo(uh.z); ah[5]=bfhi(uh.z); ah[6]=bflo(uh.w); ah[7]=bfhi(uh.w);
            aw[0]=bflo(uw.x); aw[1]=bfhi(uw.x); aw[2]=bflo(uw.y); aw[3]=bfhi(uw.y);
            aw[4]=bflo(uw.z); aw[5]=bfhi(uw.z); aw[6]=bflo(uw.w); aw[7]=bfhi(uw.w);
            #pragma unroll
            for (int kk = 0; kk < 8; ++kk) {
                float yy = vv[kk] * ah[kk] * aw[kk];
                y[j * 8 + kk] = yy;
                mu += yy;
            }
        }
        mu *= (1.0f / D_);
        float var = 0.f;
        #pragma unroll
        for (int c = 0; c < 32; ++c) { float dl = y[c] - mu; var += dl * dl; }
        var *= (1.0f / D_);
        float rs = rsqrtf(var + LN_EPS_);
        #pragma unroll
        for (int j = 0; j < 8; ++j) {
            float4 gq = ((const float4*)gamma)[j];
            float4 bt = ((const float4*)beta)[j];
            s1p[4 * j + 0] += (y[4 * j + 0] - mu) * rs * gq.x + bt.x;
            s1p[4 * j + 1] += (y[4 * j + 1] - mu) * rs * gq.y + bt.y;
            s1p[4 * j + 2] += (y[4 * j + 2] - mu) * rs * gq.z + bt.z;
            s1p[4 * j + 3] += (y[4 * j + 3] - mu) * rs * gq.w + bt.w;
        }
    }
    #pragma unroll
    for (int c = 0; c < 32; ++c) {
        float vv = s1p[c];
        vv += __shfl_xor(vv, 1);  vv += __shfl_xor(vv, 2);  vv += __shfl_xor(vv, 4);
        vv += __shfl_xor(vv, 8);  vv += __shfl_xor(vv, 16); vv += __shfl_xor(vv, 32);
        s1p[c] = vv;
    }
    if (lane == 0) {
        #pragma unroll
        for (int c = 0; c < 32; ++c) red[wv][c] = s1p[c];
    }
    __syncthreads();
    if (t < 32) {
        float a = red[0][t] + red[1][t] + red[2][t] + red[3][t];
        atomicAdd(&s1[bg * D_ + t], a);
    }
}

// ---------------------------------------------------------------------------
// K4: per-bg channel softmax of s1/3072 and s2/3072.
// ---------------------------------------------------------------------------
__global__ __launch_bounds__(64) void k4_softmax(const float* __restrict__ s1,
                                                 const float* __restrict__ s2,
                                                 float* __restrict__ x11,
                                                 float* __restrict__ x21)
{
    int bg = blockIdx.x;
    int lane = threadIdx.x;
    const float* s = (lane < 32) ? s1 : s2;
    float* o = (lane < 32) ? x11 : x21;
    int c = lane & 31;
    float v = s[bg * D_ + c] * (1.0f / (float)NPIX_);
    float m = v;
    m = fmaxf(m, __shfl_xor(m, 1));  m = fmaxf(m, __shfl_xor(m, 2));
    m = fmaxf(m, __shfl_xor(m, 4));  m = fmaxf(m, __shfl_xor(m, 8));
    m = fmaxf(m, __shfl_xor(m, 16));
    float e = expf(v - m);
    float sm = e;
    sm += __shfl_xor(sm, 1);  sm += __shfl_xor(sm, 2);
    sm += __shfl_xor(sm, 4);  sm += __shfl_xor(sm, 8);
    sm += __shfl_xor(sm, 16);
    o[bg * D_ + c] = e / sm;
}

// ---------------------------------------------------------------------------
// K5: fused conv+gate+out. grid = BG*4 (16 rows each), 512 thr (8 waves).
// Stage 18 rows fp32->bf16 swizzled LDS; MFMA conv; w1 in-register -> wbuf;
// epilogue reads gx from the LDS tile (bf16) for y, w2, AND the output:
// out = bf16(gx) * gate — no fp32 x re-read.
// ---------------------------------------------------------------------------
__global__ __launch_bounds__(512) void k5_conv(const float* __restrict__ x,
                                               const unsigned short* __restrict__ wbf,
                                               const float* __restrict__ b3,
                                               const unsigned short* __restrict__ xhb,
                                               const unsigned short* __restrict__ xwb,
                                               const float* __restrict__ gamma,
                                               const float* __restrict__ beta,
                                               const float* __restrict__ x11,
                                               const float* __restrict__ x21,
                                               float* __restrict__ out)
{
    __shared__ unsigned short sbuf[18 * W_ * D_];   // 55296 B
    __shared__ float wbuf[16][W_];                  // 3072 B
    int bi = blockIdx.x;
    int bg = bi >> 2;
    int h0 = (bi & 3) << 4;             // 16 output rows per block
    int b = bg >> 3, gi = bg & 7;
    const float* base = x + (size_t)b * H_ * W_ * C_ + gi * D_;
    int t = threadIdx.x;
    int lane = t & 63;
    int wv = t >> 6;
    const int e0 = lane & 15;
    const int ko = (lane >> 4) << 3;

    bf16x8 wf[9][2];
    #pragma unroll
    for (int tp = 0; tp < 9; ++tp)
        #pragma unroll
        for (int n = 0; n < 2; ++n)
            wf[tp][n] = *(const bf16x8*)(const void*)(wbf + (((tp << 5) + (n << 4) + e0) << 5) + ko);
    float be0 = b3[e0], be1 = b3[e0 + 16];
    float a110 = x11[bg * D_ + e0], a111 = x11[bg * D_ + e0 + 16];

    // stage 18 rows (h0-1 .. h0+16), zero outside image. 6912 uint2 chunks.
    #pragma unroll
    for (int kk = 0; kk < 14; ++kk) {
        int i = t + (kk << 9);
        if (i < 6912) {
            int r = i / 384;
            int rem = i - r * 384;
            int w = rem >> 3, cc = rem & 7;
            int hh = h0 - 1 + r;
            unsigned u0 = 0, u1 = 0;
            if (hh >= 0 && hh < H_) {
                float4 v = *(const float4*)(base + (size_t)(hh * W_ + w) * C_ + (cc << 2));
                u0 = (unsigned)f2bf(v.x) | ((unsigned)f2bf(v.y) << 16);
                u1 = (unsigned)f2bf(v.z) | ((unsigned)f2bf(v.w) << 16);
            }
            int addr = r * SROWB + ((((w << 6) + (cc << 3))) ^ ((w & 7) << 4));
            *(uint2*)((char*)sbuf + addr) = make_uint2(u0, u1);
        }
    }
    __syncthreads();

    int swz9[9]; bool inv9[9];
    #pragma unroll
    for (int m = 0; m < 3; ++m)
        #pragma unroll
        for (int dw = 0; dw < 3; ++dw) {
            int pxi = (m << 4) + e0 + dw - 1;
            int pxc = pxi < 0 ? 0 : (pxi > 47 ? 47 : pxi);
            swz9[m * 3 + dw] = swz16(pxc, lane >> 4);
            inv9[m * 3 + dw] = (pxi != pxc);
        }
    const bf16x8 z8 = {0, 0, 0, 0, 0, 0, 0, 0};

    // MFMA: each wave 2 rows x 3 m-tiles
    for (int q = 0; q < 2; ++q) {
        int r = (wv << 1) + q;
        #pragma unroll
        for (int m = 0; m < 3; ++m) {
            f32x4 acc0 = {be0, be0, be0, be0};
            f32x4 acc1 = {be1, be1, be1, be1};
            #pragma unroll
            for (int dh = 0; dh < 3; ++dh) {
                int srowB = (r + dh) * SROWB;
                #pragma unroll
                for (int dw = 0; dw < 3; ++dw) {
                    bf16x8 a = *(const bf16x8*)(const void*)((const char*)sbuf + srowB + swz9[m * 3 + dw]);
                    if ((m == 0 && dw == 0) || (m == 2 && dw == 2)) {
                        if (inv9[m * 3 + dw]) a = z8;
                    }
                    acc0 = __builtin_amdgcn_mfma_f32_16x16x32_bf16(a, wf[dh * 3 + dw][0], acc0, 0, 0, 0);
                    acc1 = __builtin_amdgcn_mfma_f32_16x16x32_bf16(a, wf[dh * 3 + dw][1], acc1, 0, 0, 0);
                }
            }
            // w1[pixel] = sum_e x11[e]*x2[pixel][e]
            #pragma unroll
            for (int rg = 0; rg < 4; ++rg) {
                float p = a110 * acc0[rg] + a111 * acc1[rg];
                p += __shfl_xor(p, 1); p += __shfl_xor(p, 2);
                p += __shfl_xor(p, 4); p += __shfl_xor(p, 8);
                if (e0 == 0) wbuf[r][(m << 4) + ((lane >> 4) << 2) + rg] = p;
            }
        }
    }
    __syncthreads();

    // epilogue: 768 px, gx from LDS bf16
    for (int p = t; p < 16 * W_; p += 512) {
        int r = p / W_;
        int w = p - r * W_;
        int h = h0 + r;
        int srowB = (r + 1) * SROWB;
        const uint4* ph4 = (const uint4*)(xhb + (((size_t)bg << 6) + h) * D_);
        const uint4* pw4 = (const uint4*)(xwb + ((size_t)bg * W_ + w) * D_);
        float v[32], y[32];
        float mu = 0.f;
        #pragma unroll
        for (int j = 0; j < 4; ++j) {
            uint4 uv = *(const uint4*)((const char*)sbuf + srowB + swz16(w, j));
            uint4 uh = ph4[j];
            uint4 uw = pw4[j];
            float ah[8], aw[8];
            v[j*8+0]=bflo(uv.x); v[j*8+1]=bfhi(uv.x); v[j*8+2]=bflo(uv.y); v[j*8+3]=bfhi(uv.y);
            v[j*8+4]=bflo(uv.z); v[j*8+5]=bfhi(uv.z); v[j*8+6]=bflo(uv.w); v[j*8+7]=bfhi(uv.w);
            ah[0]=bflo(uh.x); ah[1]=bfhi(uh.x); ah[2]=bflo(uh.y); ah[3]=bfhi(uh.y);
            ah[4]=bflo(uh.z); ah[5]=bfhi(uh.z); ah[6]=bflo(uh.w); ah[7]=bfhi(uh.w);
            aw[0]=bflo(uw.x); aw[1]=bfhi(uw.x); aw[2]=bflo(uw.y); aw[3]=bfhi(uw.y);
            aw[4]=bflo(uw.z); aw[5]=bfhi(uw.z); aw[6]=bflo(uw.w); aw[7]=bfhi(uw.w);
            #pragma unroll
            for (int kk = 0; kk < 8; ++kk) {
                float yy = v[j * 8 + kk] * ah[kk] * aw[kk];
                y[j * 8 + kk] = yy;
                mu += yy;
            }
        }
        mu *= (1.0f / D_);
        float var = 0.f;
        #pragma unroll
        for (int c = 0; c < D_; ++c) { float dl = y[c] - mu; var += dl * dl; }
        var *= (1.0f / D_);
        float rs = rsqrtf(var + LN_EPS_);

        float w2 = 0.f;
        #pragma unroll
        for (int c = 0; c < D_; ++c) {
            float x1v = (y[c] - mu) * rs * gamma[c] + beta[c];
            w2 += x21[bg * D_ + c] * x1v;
        }
        float gate = sigmoidf_(wbuf[r][w] + w2);

        float4* op = (float4*)(out + (size_t)b * H_ * W_ * C_ + (size_t)(h * W_ + w) * C_ + gi * D_);
        #pragma unroll
        for (int j = 0; j < 8; ++j) {
            float4 tq;
            tq.x = v[4 * j + 0] * gate; tq.y = v[4 * j + 1] * gate;
            tq.z = v[4 * j + 2] * gate; tq.w = v[4 * j + 3] * gate;
            op[j] = tq;
        }
    }
}

extern "C" void kernel_launch(void* const* d_in, const int* in_sizes, int n_in,
                              void* d_out, int out_size, void* d_ws, size_t ws_size,
                              hipStream_t stream)
{
    const float* x     = (const float*)d_in[0];
    const float* w1    = (const float*)d_in[1];
    const float* b1    = (const float*)d_in[2];
    const float* w3    = (const float*)d_in[3];
    const float* b3    = (const float*)d_in[4];
    const float* gamma = (const float*)d_in[5];
    const float* beta  = (const float*)d_in[6];

    char* wsb = (char*)d_ws;
    unsigned short* xhb = (unsigned short*)wsb;                 // 1,048,576 B
    unsigned short* xwb = (unsigned short*)(wsb + 1048576);     //   786,432 B
    float* s1  = (float*)(wsb + 1835008);                       //    32,768 B
    float* s2  = (float*)(wsb + 1867776);
    float* x11 = (float*)(wsb + 1900544);
    float* x21 = (float*)(wsb + 1933312);
    unsigned short* wbf = (unsigned short*)(wsb + 1966080);     //    18,432 B

    hipMemsetAsync(s1, 0, 32768, stream);

    k0_prep<<<36, 256, 0, stream>>>(w3, wbf);
    k1_sums<<<BG_, 512, 0, stream>>>(x, w1, b1, w3, b3, xhb, xwb, s2);
    k2_s1<<<BG_ * 4, 256, 0, stream>>>(x, xhb, xwb, gamma, beta, s1);
    k4_softmax<<<BG_, 64, 0, stream>>>(s1, s2, x11, x21);
    k5_conv<<<BG_ * 4, 512, 0, stream>>>(x, wbf, b3, xhb, xwb, gamma, beta, x11, x21,
                                         (float*)d_out);
}